// Round 5
// baseline (667.006 us; speedup 1.0000x reference)
//
#include <hip/hip_runtime.h>
#include <hip/hip_bf16.h>

// MLA prefill: B=2,S=2048,D=2048,H=16,DQK=128(=64 nope+64 rope),DV=128,QLR=1536,KVLR=1024
// INPUTS FP32; OUTPUT FP32. R14 (on top of R13=546.6us):
//  (a) gemm_bt: 2-phase LDS double-buffer re-added (T3-min): STAGE(next) via
//      global_load_lds BEFORE compute of current; ONE barrier per K-step.
//      (Audited: uniform buf idx, lane-linear LDS dest, affine global src.)
//  (b) attn: finer blocks for tail packing -- 256 thr / 4 waves, QBLK=32,
//      pairing (x, 63-x) keeps per-block compute at 33 tile-units; grid
//      32x16x2 = 1024 blocks (4/CU initial vs 2/CU before). Per-wave math
//      identical to R13 (swapped QK^T, per-lane softmax). NO divergent-base
//      global_load_lds anywhere (banned construct, suspected R11/R12 killer).
// No __expf (container-killer). No INFINITY (finite-math safe).
//
// Workspace (67.7 MiB):
//   kv2 @ 0         (4096x3072 bf16, 25.2MB)  live: kv2-gemm .. attn
//   kpe @ 25165824  (4096x64  bf16,  0.5MB)   live: rope_k .. attn
//   X   @ 25690112  (16.8MB, time-shared): kvb -> qa -> attno
//   xb  @ 43319296  (4096x2048 bf16, 16.8MB)  live: cvt .. qa-gemm
//   W   @ 60096512  (8.4MB weight slot, reused: wkv_a,wkv_b,wq_a,wq_b,wo)
//   qbuf (4096x2048 bf16) lives in d_out until out-gemm.

using bf16 = __hip_bfloat16;
typedef __attribute__((ext_vector_type(8))) short bf16x8;
typedef __attribute__((ext_vector_type(4))) float f32x4;

#define S_ 2048
#define NEG_BIG (-1e30f)
#define LOG2E 1.4426950408889634f

static __device__ __forceinline__ f32x4 mfma16(bf16x8 a, bf16x8 b, f32x4 c) {
    return __builtin_amdgcn_mfma_f32_16x16x32_bf16(a, b, c, 0, 0, 0);
}

// async global->LDS, 16B per lane. LDS dest must be lane-linear per wave;
// global src must be a single affine base (no divergent base select!).
static __device__ __forceinline__ void gload_lds16(const bf16* g, bf16* l) {
    __builtin_amdgcn_global_load_lds(
        (const __attribute__((address_space(1))) void*)g,
        (__attribute__((address_space(3))) void*)l, 16, 0, 0);
}

// ---------------------------------------------------------------------------
// fp32 -> bf16 bulk convert, 4 elems/thread.
// ---------------------------------------------------------------------------
__global__ __launch_bounds__(256) void f2b(const float* __restrict__ src,
                                           bf16* __restrict__ dst, int n4) {
    int i = blockIdx.x * 256 + threadIdx.x;
    if (i < n4) {
        float4 v = ((const float4*)src)[i];
        alignas(8) bf16 t[4];
        t[0] = (bf16)v.x; t[1] = (bf16)v.y; t[2] = (bf16)v.z; t[3] = (bf16)v.w;
        ((uint2*)dst)[i] = *(const uint2*)t;
    }
}

// ---------------------------------------------------------------------------
// GEMM: C[M,N] = A[M,K] @ B[N,K]^T. 128x128 tile, BK=32, 256 thr, bf16 in.
// Double-buffered staging via global_load_lds; swizzle on GLOBAL src address,
// LDS linear. One __syncthreads per K-step (its implicit vmcnt(0)+lgkmcnt(0)
// drain completes both the prefetch DMA and this step's LDS reads).
// NOTE: no N-guard in staging -- caller guarantees B rows up to grid.y*128
// readable (ragged N=1088 reads junk rows; cols>=N never stored).
// ---------------------------------------------------------------------------
template <bool C_F32>
__global__ __launch_bounds__(256) void gemm_bt(const bf16* __restrict__ A,
                                               const bf16* __restrict__ Bw,
                                               void* __restrict__ Cv,
                                               int M, int N, int K,
                                               int lda, int ldb, int ldc) {
    __shared__ bf16 As[2][128 * 32];
    __shared__ bf16 Bs[2][128 * 32];
    const int tid = threadIdx.x;
    const int m0 = blockIdx.x * 128;
    const int n0 = blockIdx.y * 128;
    const int w = tid >> 6, lane = tid & 63, quad = lane >> 4, l15 = lane & 15;
    const int wr = (w >> 1) * 64, wc = (w & 1) * 64;

    f32x4 acc[4][4];
#pragma unroll
    for (int i = 0; i < 4; i++)
#pragma unroll
        for (int j = 0; j < 4; j++) acc[i][j] = (f32x4){0.f, 0.f, 0.f, 0.f};

    auto stage = [&](int buf, int k0) {
#pragma unroll
        for (int cc = 0; cc < 2; cc++) {
            int c = tid + cc * 256;            // 512 chunks of 8 bf16 per matrix
            int row = c >> 2;
            int chunk = (c & 3) ^ ((row >> 1) & 3);  // pre-swizzled source
            gload_lds16(A + (size_t)(m0 + row) * lda + k0 + chunk * 8, &As[buf][c * 8]);
            gload_lds16(Bw + (size_t)(n0 + row) * ldb + k0 + chunk * 8, &Bs[buf][c * 8]);
        }
    };

    stage(0, 0);
    __syncthreads();                // drains vmcnt(0): buf0 ready
    int cur = 0;
    for (int k0 = 0; k0 < K; k0 += 32) {
        if (k0 + 32 < K) stage(cur ^ 1, k0 + 32);   // async prefetch next tile
        const bf16* Asc = As[cur];
        const bf16* Bsc = Bs[cur];
        bf16x8 af[4], bfr[4];
#pragma unroll
        for (int mi = 0; mi < 4; mi++) {
            int row = wr + mi * 16 + l15;
            int chunkE = quad ^ ((row >> 1) & 3);
            af[mi] = *(const bf16x8*)(&Asc[row * 32 + chunkE * 8]);
        }
#pragma unroll
        for (int ni = 0; ni < 4; ni++) {
            int row = wc + ni * 16 + l15;
            int chunkE = quad ^ ((row >> 1) & 3);
            bfr[ni] = *(const bf16x8*)(&Bsc[row * 32 + chunkE * 8]);
        }
#pragma unroll
        for (int mi = 0; mi < 4; mi++)
#pragma unroll
            for (int ni = 0; ni < 4; ni++)
                acc[mi][ni] = mfma16(af[mi], bfr[ni], acc[mi][ni]);
        __syncthreads();            // prefetch DMA + LDS reads drained; all waves
        cur ^= 1;
    }

#pragma unroll
    for (int mi = 0; mi < 4; mi++) {
#pragma unroll
        for (int ni = 0; ni < 4; ni++) {
            int col = n0 + wc + ni * 16 + l15;
            if (col < N) {
#pragma unroll
                for (int r = 0; r < 4; r++) {
                    int row = m0 + wr + mi * 16 + quad * 4 + r;
                    if (C_F32) ((float*)Cv)[(size_t)row * ldc + col] = acc[mi][ni][r];
                    else       ((bf16*)Cv)[(size_t)row * ldc + col] = (bf16)acc[mi][ni][r];
                }
            }
        }
    }
}

// ---------------------------------------------------------------------------
// In-place row RMSNorm on bf16 buffer, fp32 weight, fp32 stats.
// ---------------------------------------------------------------------------
__global__ void rmsnorm_ip(bf16* __restrict__ buf, const float* __restrict__ w,
                           int cols, int ld) {
    int row = blockIdx.x;
    bf16* p = buf + (size_t)row * ld;
    float ss = 0.f;
    for (int c = threadIdx.x; c < cols; c += 256) {
        float v = __bfloat162float(p[c]);
        ss += v * v;
    }
#pragma unroll
    for (int off = 32; off; off >>= 1) ss += __shfl_down(ss, off, 64);
    __shared__ float red[4];
    __shared__ float rnorm_s;
    if ((threadIdx.x & 63) == 0) red[threadIdx.x >> 6] = ss;
    __syncthreads();
    if (threadIdx.x == 0)
        rnorm_s = rsqrtf((red[0] + red[1] + red[2] + red[3]) / cols + 1e-6f);
    __syncthreads();
    float rn = rnorm_s;
    for (int c = threadIdx.x; c < cols; c += 256) {
        float v = __bfloat162float(p[c]);
        p[c] = (bf16)(v * rn * w[c]);
    }
}

// ---------------------------------------------------------------------------
// RoPE on k_pe: kpe[row,0..64) = rope(kvb[row,1024..1088)). fp32 freqs.
// ---------------------------------------------------------------------------
__global__ void rope_k(const bf16* __restrict__ kvb, bf16* __restrict__ kpe,
                       const float* __restrict__ fc, const float* __restrict__ fs) {
    int id = blockIdx.x * 256 + threadIdx.x;  // ROWS*32
    int row = id >> 5, i = id & 31;
    int s = row & (S_ - 1);
    const bf16* p = kvb + (size_t)row * 1088 + 1024 + 2 * i;
    float x0 = __bfloat162float(p[0]), x1 = __bfloat162float(p[1]);
    float c = fc[s * 32 + i], sn = fs[s * 32 + i];
    bf16* q = kpe + (size_t)row * 64 + 2 * i;
    q[0] = (bf16)(x0 * c - x1 * sn);
    q[1] = (bf16)(x0 * sn + x1 * c);
}

// RoPE on q_pe, in-place on bf16 qbuf: [row, h*128+64 .. h*128+128)
__global__ void rope_q(bf16* __restrict__ qb, const float* __restrict__ fc,
                       const float* __restrict__ fs) {
    int id = blockIdx.x * 256 + threadIdx.x;  // ROWS*16*32
    int row = id >> 9, rest = id & 511, h = rest >> 5, i = rest & 31;
    int s = row & (S_ - 1);
    bf16* p = qb + (size_t)row * 2048 + h * 128 + 64 + 2 * i;
    float x0 = __bfloat162float(p[0]), x1 = __bfloat162float(p[1]);
    float c = fc[s * 32 + i], sn = fs[s * 32 + i];
    p[0] = (bf16)(x0 * c - x1 * sn);
    p[1] = (bf16)(x0 * sn + x1 * c);
}

// ---------------------------------------------------------------------------
// MFMA flash attention, causal, SWAPPED QK^T. Block = 256 thr = 4 waves,
// 2 groups x 2 waves; group 0 q-tile jA=blockIdx.x (32 rows), group 1 q-tile
// jB=63-jA (balance: 33 compute tile-units per block). KVBLK=64.
// Each lane's q-row: qrow = q0 + wl*16 + l15. sc = mfma(K,Q) => D[t][q]:
// row max/sum in-lane + shfl_xor(16|32); m/l per-lane scalars.
// K staged by register int4 + swizzled ds_write_b128 (proven construct).
// ---------------------------------------------------------------------------
__global__ __launch_bounds__(256) void attn_kernel(const bf16* __restrict__ Qg,
                                                   const bf16* __restrict__ KV2,
                                                   const bf16* __restrict__ KPE,
                                                   bf16* __restrict__ Og) {
    __shared__ bf16 Ks[64 * 128];       // [t][d], 16B-chunk swizzle cE = c8 ^ (t&7)
    __shared__ bf16 Vt[128 * 64];       // [dv][t], swizzle cE = (t>>3) ^ (dv&7)
    __shared__ bf16 Ps[4][16 * 64];     // per-wave P [q16][t64], cE = c8 ^ (q&7)
    const int tid = threadIdx.x;
    const int h = blockIdx.y;
    const int b = blockIdx.z;
    const int w = tid >> 6, lane = tid & 63, quad = lane >> 4, l15 = lane & 15;
    const int grp = w >> 1, wl = w & 1;
    const int jB = 63 - (int)blockIdx.x;
    const int q0 = (grp ? jB : (int)blockIdx.x) * 32;
    const int qrow = q0 + wl * 16 + l15;          // this lane's q row (in S)
    const float scl2 = 0.08838834764831845f * LOG2E;  // 1/sqrt(128) * log2(e)

    // Q as B-fragment: lane holds col q=l15(own row), k = kk*32 + quad*8 + j
    bf16x8 qf[4];
    {
        const bf16* qp = Qg + ((size_t)(b * S_) + qrow) * 2048 + h * 128 + quad * 8;
#pragma unroll
        for (int kk = 0; kk < 4; kk++) qf[kk] = *(const bf16x8*)(qp + kk * 32);
    }

    f32x4 acc_o[8];
#pragma unroll
    for (int j = 0; j < 8; j++) acc_o[j] = (f32x4){0.f, 0.f, 0.f, 0.f};
    float m_i = NEG_BIG, l_i = 0.f;               // per-lane (q = qrow)
    const int s_base = q0 + wl * 16 + quad * 4;   // acc_o row base (PV C-layout)
    const int tend = jB * 32;                     // block-uniform loop bound

    for (int t0 = 0; t0 <= tend; t0 += 64) {
        __syncthreads();
        // ---- stage K: register int4 + swizzled ds_write (4 per thread) ----
#pragma unroll
        for (int cc = 0; cc < 4; cc++) {
            int c = tid + cc * 256;               // 1024 chunks of 8
            int trow = c >> 4, chunk = c & 15;
            int col8 = chunk * 8;
            size_t grow = (size_t)(b * S_) + t0 + trow;
            int4 v;
            if (col8 < 64) v = *(const int4*)(KV2 + grow * 3072 + h * 192 + col8);
            else           v = *(const int4*)(KPE + grow * 64 + col8 - 64);
            int chunkE = chunk ^ (trow & 7);
            *(int4*)(&Ks[trow * 128 + chunkE * 8]) = v;
        }
        // ---- stage V: 4x4 register transpose, 2 units per thread ----
#pragma unroll
        for (int vv = 0; vv < 2; vv++) {
            int u = tid + vv * 256;               // 512 (t4 x dv4) units
            int dv0 = (u >> 4) * 4;               // 0..124
            int tv0 = (u & 15) * 4;               // 0..60
            size_t grow0 = (size_t)(b * S_) + t0 + tv0;
            alignas(16) bf16 va[4][4];
#pragma unroll
            for (int i = 0; i < 4; i++)
                *(uint2*)va[i] = *(const uint2*)(KV2 + (grow0 + i) * 3072 + h * 192 + 64 + dv0);
#pragma unroll
            for (int j = 0; j < 4; j++) {
                alignas(8) bf16 tmp[4] = {va[0][j], va[1][j], va[2][j], va[3][j]};
                int dv = dv0 + j;
                int cE = (tv0 >> 3) ^ (dv & 7);
                *(uint2*)(&Vt[dv * 64 + cE * 8 + (tv0 & 7)]) = *(uint2*)tmp;
            }
        }
        __syncthreads();
        if (t0 > q0) continue;   // this group's causal range done; keep staging

        // ---- scores, swapped: sc[ni] = K_tile(ni) x Q  => D[t][q] ----
        f32x4 sc[4];
#pragma unroll
        for (int ni = 0; ni < 4; ni++) sc[ni] = (f32x4){0.f, 0.f, 0.f, 0.f};
#pragma unroll
        for (int kk = 0; kk < 4; kk++) {
#pragma unroll
            for (int ni = 0; ni < 4; ni++) {
                int trow = ni * 16 + l15;
                int chunkE = (kk * 4 + quad) ^ (trow & 7);
                bf16x8 kf = *(const bf16x8*)(&Ks[trow * 128 + chunkE * 8]);
                sc[ni] = mfma16(kf, qf[kk], sc[ni]);   // A=K rows t, B=Q cols q
            }
        }
        // ---- per-lane softmax over the full row (t in lane) ----
        float xv[4][4];
        float pmax = NEG_BIG;
#pragma unroll
        for (int ni = 0; ni < 4; ni++) {
#pragma unroll
            for (int r = 0; r < 4; r++) {
                int t = t0 + ni * 16 + quad * 4 + r;
                float x = sc[ni][r] * scl2;
                if (t > qrow) x = NEG_BIG;
                xv[ni][r] = x;
                pmax = fmaxf(pmax, x);
            }
        }
        pmax = fmaxf(pmax, __shfl_xor(pmax, 16, 64));
        pmax = fmaxf(pmax, __shfl_xor(pmax, 32, 64));
        float mn = fmaxf(m_i, pmax);
        float alpha = exp2f(m_i - mn);
        m_i = mn;
        float rsum = 0.f;
#pragma unroll
        for (int ni = 0; ni < 4; ni++)
#pragma unroll
            for (int r = 0; r < 4; r++) {
                float e = exp2f(xv[ni][r] - mn);
                xv[ni][r] = e;
                rsum += e;
            }
        rsum += __shfl_xor(rsum, 16, 64);
        rsum += __shfl_xor(rsum, 32, 64);
        l_i = l_i * alpha + rsum;
        // alpha for acc_o rows (q-in-16 = quad*4+r) lives at lane l15=quad*4+r
        float ar[4];
#pragma unroll
        for (int r = 0; r < 4; r++) ar[r] = __shfl(alpha, quad * 4 + r, 64);
#pragma unroll
        for (int nj = 0; nj < 8; nj++)
#pragma unroll
            for (int r = 0; r < 4; r++) acc_o[nj][r] *= ar[r];

        // ---- P -> LDS: 4 packed b64 writes (t runs of 4 in-lane) ----
#pragma unroll
        for (int ni = 0; ni < 4; ni++) {
            int tb = ni * 16 + quad * 4;          // t base (elems)
            int cE = (tb >> 3) ^ (l15 & 7);
            alignas(8) bf16 tmp[4] = {(bf16)xv[ni][0], (bf16)xv[ni][1],
                                      (bf16)xv[ni][2], (bf16)xv[ni][3]};
            *(uint2*)(&Ps[w][l15 * 64 + cE * 8 + (tb & 7)]) = *(uint2*)tmp;
        }
        // ---- O += P @ V (wave-private Ps; in-wave DS ordering suffices) ----
#pragma unroll
        for (int kk2 = 0; kk2 < 2; kk2++) {
            int cEp = (kk2 * 4 + quad) ^ (l15 & 7);
            bf16x8 pf = *(const bf16x8*)(&Ps[w][l15 * 64 + cEp * 8]);
#pragma unroll
            for (int nj = 0; nj < 8; nj++) {
                int dv = nj * 16 + l15;
                int chunkE = (kk2 * 4 + quad) ^ (dv & 7);
                bf16x8 vf = *(const bf16x8*)(&Vt[dv * 64 + chunkE * 8]);
                acc_o[nj] = mfma16(pf, vf, acc_o[nj]);
            }
        }
    }
    // epilogue: l for acc rows fetched from lane l15 = quad*4+r
    float lr[4];
#pragma unroll
    for (int r = 0; r < 4; r++) lr[r] = __shfl(l_i, quad * 4 + r, 64);
#pragma unroll
    for (int nj = 0; nj < 8; nj++) {
        int col = h * 128 + nj * 16 + l15;
#pragma unroll
        for (int r = 0; r < 4; r++) {
            float v = acc_o[nj][r] / lr[r];
            Og[((size_t)(b * S_) + s_base + r) * 2048 + col] = (bf16)v;
        }
    }
}

// ---------------------------------------------------------------------------
extern "C" void kernel_launch(void* const* d_in, const int* in_sizes, int n_in,
                              void* d_out, int out_size, void* d_ws, size_t ws_size,
                              hipStream_t stream) {
    const float* x        = (const float*)d_in[0];   // (4096, 2048) fp32
    const float* wq_a     = (const float*)d_in[1];   // (1536, 2048) fp32
    const float* q_norm_w = (const float*)d_in[2];   // (1536,) fp32
    const float* wq_b     = (const float*)d_in[3];   // (2048, 1536) fp32
    const float* wkv_a    = (const float*)d_in[4];   // (1088, 2048) fp32
    const float* kv_norm_w= (const float*)d_in[5];   // (1024,) fp32
    const float* wkv_b    = (const float*)d_in[6];   // (3072, 1024) fp32
    const float* wo       = (const float*)d_in[7];   // (2048, 2048) fp32
    const float* fcos     = (const float*)d_in[9];   // (2048, 32) fp32
    const float* fsin     = (const float*)d_in[10];  // (2048, 32) fp32
    float* out = (float*)d_out;                      // (4096, 2048) fp32

    char* ws = (char*)d_ws;
    bf16* kv2   = (bf16*)(ws);                  // 25.2MB
    bf16* kpe   = (bf16*)(ws + 25165824);       // 0.5MB
    bf16* kvb   = (bf16*)(ws + 25690112);       // } region X (16.8MB,
    bf16* qa    = (bf16*)(ws + 25690112);       // }  time-shared)
    bf16* attno = (bf16*)(ws + 25690112);       // }
    bf16* xb    = (bf16*)(ws + 43319296);       // 16.8MB
    bf16* wslot = (bf16*)(ws + 60096512);       // 8.4MB reusable weight slot
    bf16* qbuf  = (bf16*)d_out;                 // bf16 in d_out

    dim3 blk(256);
    // ---- convert x once ----
    f2b<<<8192, blk, 0, stream>>>(x, xb, 2097152);
    // ---- KV path ----
    f2b<<<2176, blk, 0, stream>>>(wkv_a, wslot, 557056);   // 1088*2048/4
    // N=1088 ragged: staging reads wslot rows up to 1151 (junk ok, cols>=1088
    // never stored); 1152*2048*2 = 4.72MB < 8.4MB slot.
    gemm_bt<false><<<dim3(32, 9), blk, 0, stream>>>(xb, wslot, kvb, 4096, 1088, 2048, 2048, 2048, 1088);
    rope_k<<<512, blk, 0, stream>>>(kvb, kpe, fcos, fsin);
    rmsnorm_ip<<<4096, blk, 0, stream>>>(kvb, kv_norm_w, 1024, 1088);
    f2b<<<3072, blk, 0, stream>>>(wkv_b, wslot, 786432);   // 3072*1024/4
    gemm_bt<false><<<dim3(32, 24), blk, 0, stream>>>(kvb, wslot, kv2, 4096, 3072, 1024, 1088, 1024, 3072);
    // ---- Q path (region X becomes qa; qbuf in d_out) ----
    f2b<<<3072, blk, 0, stream>>>(wq_a, wslot, 786432);    // 1536*2048/4
    gemm_bt<false><<<dim3(32, 12), blk, 0, stream>>>(xb, wslot, qa, 4096, 1536, 2048, 2048, 2048, 1536);
    rmsnorm_ip<<<4096, blk, 0, stream>>>(qa, q_norm_w, 1536, 1536);
    f2b<<<3072, blk, 0, stream>>>(wq_b, wslot, 786432);    // 2048*1536/4
    gemm_bt<false><<<dim3(32, 16), blk, 0, stream>>>(qa, wslot, qbuf, 4096, 2048, 1536, 1536, 1536, 2048);
    rope_q<<<8192, blk, 0, stream>>>(qbuf, fcos, fsin);
    // ---- attention (finer paired blocks; region X becomes attno) ----
    attn_kernel<<<dim3(32, 16, 2), dim3(256), 0, stream>>>(qbuf, kv2, kpe, attno);
    // ---- output projection (fp32 store) ----
    f2b<<<4096, blk, 0, stream>>>(wo, wslot, 1048576);     // 2048*2048/4
    gemm_bt<true><<<dim3(32, 16), blk, 0, stream>>>(attno, wslot, out, 4096, 2048, 2048, 2048, 2048, 2048);
}

// Round 6
// 542.915 us; speedup vs baseline: 1.2286x; 1.2286x over previous
//
#include <hip/hip_runtime.h>
#include <hip/hip_bf16.h>

// MLA prefill: B=2,S=2048,D=2048,H=16,DQK=128(=64 nope+64 rope),DV=128,QLR=1536,KVLR=1024
// INPUTS FP32; OUTPUT FP32. R15 (post R14-regression analysis):
//  (a) attn: REVERT to R13 shape (512 thr, QBLK=64, pair x/31-x; staging
//      amortized over 128 q-rows/tile) + T14 async-STAGE split (next tile's
//      K/V held in regs, loads issued before barrier(b) so HBM latency hides
//      under compute; ds_write at next iteration top) + T13 defer-rescale
//      (!__all(pmax-m<=8) guard skips alpha/rescale most tiles).
//  (b) gemm: keep R14 2-phase dbuf. FUSE the two xb GEMMs (wkv_a N=1088 @
//      1.1 blk/CU + wq_a N=1536 @ 1.5 blk/CU) into one N=2624 dispatch
//      (672 blocks = 2.6/CU) writing combined cq[4096][2624].
//  BANNED: divergent-base global_load_lds (R11/R12 container killer).
// No __expf (container-killer). No INFINITY (finite-math safe).
//
// Workspace map (74.98MB used; 80MB proven writable in R1):
//   kv2  @ 0         (4096x3072 bf16, 25.2MB)  live: kv2-gemm .. attn
//   kpe  @ 25165824  (4096x64  bf16,  0.5MB)   live: rope_k .. attn
//   cq   @ 25690112  (4096x2624 bf16, 21.5MB)  cols 0-1087=kvb, 1088-2623=qa
//                    reused as attno (4096x2048) after q_b gemm.
//   xb   @ 47185920  (4096x2048 bf16, 16.8MB)  live: cvt .. fused gemm
//   wslot@ 63963136  (11.0MB weight slot: wkv_a+wq_a fused / wkv_b / wq_b / wo)
//   qbuf (4096x2048 bf16) lives in d_out until out-gemm.

using bf16 = __hip_bfloat16;
typedef __attribute__((ext_vector_type(8))) short bf16x8;
typedef __attribute__((ext_vector_type(4))) float f32x4;

#define S_ 2048
#define NEG_BIG (-1e30f)
#define LOG2E 1.4426950408889634f

static __device__ __forceinline__ f32x4 mfma16(bf16x8 a, bf16x8 b, f32x4 c) {
    return __builtin_amdgcn_mfma_f32_16x16x32_bf16(a, b, c, 0, 0, 0);
}

// async global->LDS, 16B per lane. LDS dest must be lane-linear per wave;
// global src must be a single affine base (no divergent base select!).
static __device__ __forceinline__ void gload_lds16(const bf16* g, bf16* l) {
    __builtin_amdgcn_global_load_lds(
        (const __attribute__((address_space(1))) void*)g,
        (__attribute__((address_space(3))) void*)l, 16, 0, 0);
}

// ---------------------------------------------------------------------------
// fp32 -> bf16 bulk convert, 4 elems/thread.
// ---------------------------------------------------------------------------
__global__ __launch_bounds__(256) void f2b(const float* __restrict__ src,
                                           bf16* __restrict__ dst, int n4) {
    int i = blockIdx.x * 256 + threadIdx.x;
    if (i < n4) {
        float4 v = ((const float4*)src)[i];
        alignas(8) bf16 t[4];
        t[0] = (bf16)v.x; t[1] = (bf16)v.y; t[2] = (bf16)v.z; t[3] = (bf16)v.w;
        ((uint2*)dst)[i] = *(const uint2*)t;
    }
}

// ---------------------------------------------------------------------------
// GEMM: C[M,N] = A[M,K] @ B[N,K]^T. 128x128 tile, BK=32, 256 thr, bf16 in.
// Double-buffered staging via global_load_lds; swizzle on GLOBAL src address,
// LDS linear. One __syncthreads per K-step (implicit vmcnt+lgkm drain).
// NOTE: no N-guard in staging -- caller guarantees B rows up to grid.y*128
// readable (ragged N reads junk rows; cols>=N never stored).
// ---------------------------------------------------------------------------
template <bool C_F32>
__global__ __launch_bounds__(256) void gemm_bt(const bf16* __restrict__ A,
                                               const bf16* __restrict__ Bw,
                                               void* __restrict__ Cv,
                                               int M, int N, int K,
                                               int lda, int ldb, int ldc) {
    __shared__ bf16 As[2][128 * 32];
    __shared__ bf16 Bs[2][128 * 32];
    const int tid = threadIdx.x;
    const int m0 = blockIdx.x * 128;
    const int n0 = blockIdx.y * 128;
    const int w = tid >> 6, lane = tid & 63, quad = lane >> 4, l15 = lane & 15;
    const int wr = (w >> 1) * 64, wc = (w & 1) * 64;

    f32x4 acc[4][4];
#pragma unroll
    for (int i = 0; i < 4; i++)
#pragma unroll
        for (int j = 0; j < 4; j++) acc[i][j] = (f32x4){0.f, 0.f, 0.f, 0.f};

    auto stage = [&](int buf, int k0) {
#pragma unroll
        for (int cc = 0; cc < 2; cc++) {
            int c = tid + cc * 256;            // 512 chunks of 8 bf16 per matrix
            int row = c >> 2;
            int chunk = (c & 3) ^ ((row >> 1) & 3);  // pre-swizzled source
            gload_lds16(A + (size_t)(m0 + row) * lda + k0 + chunk * 8, &As[buf][c * 8]);
            gload_lds16(Bw + (size_t)(n0 + row) * ldb + k0 + chunk * 8, &Bs[buf][c * 8]);
        }
    };

    stage(0, 0);
    __syncthreads();                // drains vmcnt(0): buf0 ready
    int cur = 0;
    for (int k0 = 0; k0 < K; k0 += 32) {
        if (k0 + 32 < K) stage(cur ^ 1, k0 + 32);   // async prefetch next tile
        const bf16* Asc = As[cur];
        const bf16* Bsc = Bs[cur];
        bf16x8 af[4], bfr[4];
#pragma unroll
        for (int mi = 0; mi < 4; mi++) {
            int row = wr + mi * 16 + l15;
            int chunkE = quad ^ ((row >> 1) & 3);
            af[mi] = *(const bf16x8*)(&Asc[row * 32 + chunkE * 8]);
        }
#pragma unroll
        for (int ni = 0; ni < 4; ni++) {
            int row = wc + ni * 16 + l15;
            int chunkE = quad ^ ((row >> 1) & 3);
            bfr[ni] = *(const bf16x8*)(&Bsc[row * 32 + chunkE * 8]);
        }
#pragma unroll
        for (int mi = 0; mi < 4; mi++)
#pragma unroll
            for (int ni = 0; ni < 4; ni++)
                acc[mi][ni] = mfma16(af[mi], bfr[ni], acc[mi][ni]);
        __syncthreads();            // prefetch DMA + LDS reads drained; all waves
        cur ^= 1;
    }

#pragma unroll
    for (int mi = 0; mi < 4; mi++) {
#pragma unroll
        for (int ni = 0; ni < 4; ni++) {
            int col = n0 + wc + ni * 16 + l15;
            if (col < N) {
#pragma unroll
                for (int r = 0; r < 4; r++) {
                    int row = m0 + wr + mi * 16 + quad * 4 + r;
                    if (C_F32) ((float*)Cv)[(size_t)row * ldc + col] = acc[mi][ni][r];
                    else       ((bf16*)Cv)[(size_t)row * ldc + col] = (bf16)acc[mi][ni][r];
                }
            }
        }
    }
}

// ---------------------------------------------------------------------------
// In-place row RMSNorm on bf16 buffer, fp32 weight, fp32 stats.
// ---------------------------------------------------------------------------
__global__ void rmsnorm_ip(bf16* __restrict__ buf, const float* __restrict__ w,
                           int cols, int ld) {
    int row = blockIdx.x;
    bf16* p = buf + (size_t)row * ld;
    float ss = 0.f;
    for (int c = threadIdx.x; c < cols; c += 256) {
        float v = __bfloat162float(p[c]);
        ss += v * v;
    }
#pragma unroll
    for (int off = 32; off; off >>= 1) ss += __shfl_down(ss, off, 64);
    __shared__ float red[4];
    __shared__ float rnorm_s;
    if ((threadIdx.x & 63) == 0) red[threadIdx.x >> 6] = ss;
    __syncthreads();
    if (threadIdx.x == 0)
        rnorm_s = rsqrtf((red[0] + red[1] + red[2] + red[3]) / cols + 1e-6f);
    __syncthreads();
    float rn = rnorm_s;
    for (int c = threadIdx.x; c < cols; c += 256) {
        float v = __bfloat162float(p[c]);
        p[c] = (bf16)(v * rn * w[c]);
    }
}

// ---------------------------------------------------------------------------
// RoPE on k_pe: kpe[row,0..64) = rope(cq[row,1024..1088)). fp32 freqs.
// cq row stride 2624 (fused buffer).
// ---------------------------------------------------------------------------
__global__ void rope_k(const bf16* __restrict__ cq, bf16* __restrict__ kpe,
                       const float* __restrict__ fc, const float* __restrict__ fs) {
    int id = blockIdx.x * 256 + threadIdx.x;  // ROWS*32
    int row = id >> 5, i = id & 31;
    int s = row & (S_ - 1);
    const bf16* p = cq + (size_t)row * 2624 + 1024 + 2 * i;
    float x0 = __bfloat162float(p[0]), x1 = __bfloat162float(p[1]);
    float c = fc[s * 32 + i], sn = fs[s * 32 + i];
    bf16* q = kpe + (size_t)row * 64 + 2 * i;
    q[0] = (bf16)(x0 * c - x1 * sn);
    q[1] = (bf16)(x0 * sn + x1 * c);
}

// RoPE on q_pe, in-place on bf16 qbuf: [row, h*128+64 .. h*128+128)
__global__ void rope_q(bf16* __restrict__ qb, const float* __restrict__ fc,
                       const float* __restrict__ fs) {
    int id = blockIdx.x * 256 + threadIdx.x;  // ROWS*16*32
    int row = id >> 9, rest = id & 511, h = rest >> 5, i = rest & 31;
    int s = row & (S_ - 1);
    bf16* p = qb + (size_t)row * 2048 + h * 128 + 64 + 2 * i;
    float x0 = __bfloat162float(p[0]), x1 = __bfloat162float(p[1]);
    float c = fc[s * 32 + i], sn = fs[s * 32 + i];
    p[0] = (bf16)(x0 * c - x1 * sn);
    p[1] = (bf16)(x0 * sn + x1 * c);
}

// ---------------------------------------------------------------------------
// MFMA flash attention, causal, SWAPPED QK^T. Block = 512 thr = 8 waves,
// 2 groups x 4 waves; group 0 q-tile blockIdx.x, group 1 q-tile 31-x.
// R13-proven structure + T14 async-STAGE split (next K/V tile in regs,
// loads overlap compute) + T13 defer-rescale.
// ---------------------------------------------------------------------------
__global__ __launch_bounds__(512) void attn_kernel(const bf16* __restrict__ Qg,
                                                   const bf16* __restrict__ KV2,
                                                   const bf16* __restrict__ KPE,
                                                   bf16* __restrict__ Og) {
    __shared__ bf16 Ks[64 * 128];       // [t][d], 16B-chunk swizzle cE = c8 ^ (t&7)
    __shared__ bf16 Vt[128 * 64];       // [dv][t], swizzle cE = (t>>3) ^ (dv&7)
    __shared__ bf16 Ps[8][16 * 64];     // per-wave P [q16][t64], cE = c8 ^ (q&7)
    const int tid = threadIdx.x;
    const int h = blockIdx.y;
    const int b = blockIdx.z;
    const int w = tid >> 6, lane = tid & 63, quad = lane >> 4, l15 = lane & 15;
    const int grp = w >> 2, wl = w & 3;
    const int jB = 31 - (int)blockIdx.x;
    const int q0 = (grp ? jB : (int)blockIdx.x) * 64;
    const int qrow = q0 + wl * 16 + l15;          // this lane's q row (in S)
    const float scl2 = 0.08838834764831845f * LOG2E;  // 1/sqrt(128) * log2(e)

    // Q as B-fragment: lane holds col q=l15(own row), k = kk*32 + quad*8 + j
    bf16x8 qf[4];
    {
        const bf16* qp = Qg + ((size_t)(b * S_) + qrow) * 2048 + h * 128 + quad * 8;
#pragma unroll
        for (int kk = 0; kk < 4; kk++) qf[kk] = *(const bf16x8*)(qp + kk * 32);
    }

    f32x4 acc_o[8];
#pragma unroll
    for (int j = 0; j < 8; j++) acc_o[j] = (f32x4){0.f, 0.f, 0.f, 0.f};
    float m_i = NEG_BIG, l_i = 0.f;               // per-lane (q = qrow)
    const int s_base = q0 + wl * 16 + quad * 4;   // acc_o row base (PV C-layout)
    const int tend = jB * 64;                     // block-uniform loop bound

    // V staging decomposition: thread -> 4t x 4dv transpose-in-regs
    const int dv0 = (tid >> 4) * 4;               // 0..124
    const int tv0 = (tid & 15) * 4;               // 0..60

    // T14: next-tile K/V held in regs (static indexing only -- rule #20)
    int4 kreg0, kreg1;
    uint2 vreg0, vreg1, vreg2, vreg3;
    auto loadKV = [&](int t0) {
        {
            int c = tid;                           // chunk 0..511
            int trow = c >> 4, chunk = c & 15, col8 = chunk * 8;
            size_t grow = (size_t)(b * S_) + t0 + trow;
            kreg0 = (col8 < 64) ? *(const int4*)(KV2 + grow * 3072 + h * 192 + col8)
                                : *(const int4*)(KPE + grow * 64 + col8 - 64);
        }
        {
            int c = tid + 512;                     // chunk 512..1023
            int trow = c >> 4, chunk = c & 15, col8 = chunk * 8;
            size_t grow = (size_t)(b * S_) + t0 + trow;
            kreg1 = (col8 < 64) ? *(const int4*)(KV2 + grow * 3072 + h * 192 + col8)
                                : *(const int4*)(KPE + grow * 64 + col8 - 64);
        }
        size_t grow0 = (size_t)(b * S_) + t0 + tv0;
        const bf16* vb = KV2 + grow0 * 3072 + h * 192 + 64 + dv0;
        vreg0 = *(const uint2*)(vb);
        vreg1 = *(const uint2*)(vb + 3072);
        vreg2 = *(const uint2*)(vb + 6144);
        vreg3 = *(const uint2*)(vb + 9216);
    };
    auto writeKV = [&]() {
        {
            int c = tid;
            int trow = c >> 4, chunk = c & 15;
            int chunkE = chunk ^ (trow & 7);
            *(int4*)(&Ks[trow * 128 + chunkE * 8]) = kreg0;
        }
        {
            int c = tid + 512;
            int trow = c >> 4, chunk = c & 15;
            int chunkE = chunk ^ (trow & 7);
            *(int4*)(&Ks[trow * 128 + chunkE * 8]) = kreg1;
        }
        const bf16* v0 = (const bf16*)&vreg0;
        const bf16* v1 = (const bf16*)&vreg1;
        const bf16* v2 = (const bf16*)&vreg2;
        const bf16* v3 = (const bf16*)&vreg3;
#pragma unroll
        for (int j = 0; j < 4; j++) {
            alignas(8) bf16 tmp[4] = {v0[j], v1[j], v2[j], v3[j]};
            int dv = dv0 + j;
            int cE = (tv0 >> 3) ^ (dv & 7);
            *(uint2*)(&Vt[dv * 64 + cE * 8 + (tv0 & 7)]) = *(uint2*)tmp;
        }
    };

    loadKV(0);                                     // prologue issue
    for (int t0 = 0; t0 <= tend; t0 += 64) {
        __syncthreads();                           // previous compute done
        writeKV();                                 // (waits vmcnt on regs)
        if (t0 + 64 <= tend) loadKV(t0 + 64);      // async: overlaps compute
        __syncthreads();                           // tile visible
        if (t0 > q0) continue;   // this group's causal range done; keep staging

        // ---- scores, swapped: sc[ni] = K_tile(ni) x Q  => D[t][q] ----
        f32x4 sc[4];
#pragma unroll
        for (int ni = 0; ni < 4; ni++) sc[ni] = (f32x4){0.f, 0.f, 0.f, 0.f};
#pragma unroll
        for (int kk = 0; kk < 4; kk++) {
#pragma unroll
            for (int ni = 0; ni < 4; ni++) {
                int trow = ni * 16 + l15;
                int chunkE = (kk * 4 + quad) ^ (trow & 7);
                bf16x8 kf = *(const bf16x8*)(&Ks[trow * 128 + chunkE * 8]);
                sc[ni] = mfma16(kf, qf[kk], sc[ni]);   // A=K rows t, B=Q cols q
            }
        }
        // ---- per-lane softmax over the full row (t in lane) ----
        float xv[4][4];
        float pmax = NEG_BIG;
#pragma unroll
        for (int ni = 0; ni < 4; ni++) {
#pragma unroll
            for (int r = 0; r < 4; r++) {
                int t = t0 + ni * 16 + quad * 4 + r;
                float x = sc[ni][r] * scl2;
                if (t > qrow) x = NEG_BIG;
                xv[ni][r] = x;
                pmax = fmaxf(pmax, x);
            }
        }
        pmax = fmaxf(pmax, __shfl_xor(pmax, 16, 64));
        pmax = fmaxf(pmax, __shfl_xor(pmax, 32, 64));
        // T13 defer-rescale: only rescale when max grew by > 8 (P <= 2^8)
        if (!__all(pmax - m_i <= 8.0f)) {
            float mn = fmaxf(m_i, pmax);
            float alpha = exp2f(m_i - mn);
            m_i = mn;
            l_i *= alpha;
            float ar[4];
#pragma unroll
            for (int r = 0; r < 4; r++) ar[r] = __shfl(alpha, quad * 4 + r, 64);
#pragma unroll
            for (int nj = 0; nj < 8; nj++)
#pragma unroll
                for (int r = 0; r < 4; r++) acc_o[nj][r] *= ar[r];
        }
        float rsum = 0.f;
#pragma unroll
        for (int ni = 0; ni < 4; ni++)
#pragma unroll
            for (int r = 0; r < 4; r++) {
                float e = exp2f(xv[ni][r] - m_i);
                xv[ni][r] = e;
                rsum += e;
            }
        rsum += __shfl_xor(rsum, 16, 64);
        rsum += __shfl_xor(rsum, 32, 64);
        l_i += rsum;

        // ---- P -> LDS: 4 packed b64 writes (t runs of 4 in-lane) ----
#pragma unroll
        for (int ni = 0; ni < 4; ni++) {
            int tb = ni * 16 + quad * 4;          // t base (elems)
            int cE = (tb >> 3) ^ (l15 & 7);
            alignas(8) bf16 tmp[4] = {(bf16)xv[ni][0], (bf16)xv[ni][1],
                                      (bf16)xv[ni][2], (bf16)xv[ni][3]};
            *(uint2*)(&Ps[w][l15 * 64 + cE * 8 + (tb & 7)]) = *(uint2*)tmp;
        }
        // ---- O += P @ V (wave-private Ps; in-wave DS ordering suffices) ----
#pragma unroll
        for (int kk2 = 0; kk2 < 2; kk2++) {
            int cEp = (kk2 * 4 + quad) ^ (l15 & 7);
            bf16x8 pf = *(const bf16x8*)(&Ps[w][l15 * 64 + cEp * 8]);
#pragma unroll
            for (int nj = 0; nj < 8; nj++) {
                int dv = nj * 16 + l15;
                int chunkE = (kk2 * 4 + quad) ^ (dv & 7);
                bf16x8 vf = *(const bf16x8*)(&Vt[dv * 64 + chunkE * 8]);
                acc_o[nj] = mfma16(pf, vf, acc_o[nj]);
            }
        }
    }
    // epilogue: l for acc rows fetched from lane l15 = quad*4+r
    float lr[4];
#pragma unroll
    for (int r = 0; r < 4; r++) lr[r] = __shfl(l_i, quad * 4 + r, 64);
#pragma unroll
    for (int nj = 0; nj < 8; nj++) {
        int col = h * 128 + nj * 16 + l15;
#pragma unroll
        for (int r = 0; r < 4; r++) {
            float v = acc_o[nj][r] / lr[r];
            Og[((size_t)(b * S_) + s_base + r) * 2048 + col] = (bf16)v;
        }
    }
}

// ---------------------------------------------------------------------------
extern "C" void kernel_launch(void* const* d_in, const int* in_sizes, int n_in,
                              void* d_out, int out_size, void* d_ws, size_t ws_size,
                              hipStream_t stream) {
    const float* x        = (const float*)d_in[0];   // (4096, 2048) fp32
    const float* wq_a     = (const float*)d_in[1];   // (1536, 2048) fp32
    const float* q_norm_w = (const float*)d_in[2];   // (1536,) fp32
    const float* wq_b     = (const float*)d_in[3];   // (2048, 1536) fp32
    const float* wkv_a    = (const float*)d_in[4];   // (1088, 2048) fp32
    const float* kv_norm_w= (const float*)d_in[5];   // (1024,) fp32
    const float* wkv_b    = (const float*)d_in[6];   // (3072, 1024) fp32
    const float* wo       = (const float*)d_in[7];   // (2048, 2048) fp32
    const float* fcos     = (const float*)d_in[9];   // (2048, 32) fp32
    const float* fsin     = (const float*)d_in[10];  // (2048, 32) fp32
    float* out = (float*)d_out;                      // (4096, 2048) fp32

    char* ws = (char*)d_ws;
    bf16* kv2   = (bf16*)(ws);                  // 25.2MB
    bf16* kpe   = (bf16*)(ws + 25165824);       // 0.5MB
    bf16* cq    = (bf16*)(ws + 25690112);       // 21.5MB combined kvb|qa; attno later
    bf16* xb    = (bf16*)(ws + 47185920);       // 16.8MB
    bf16* wslot = (bf16*)(ws + 63963136);       // 11.0MB weight slot
    bf16* attno = cq;                           // reuse after q_b gemm
    bf16* qbuf  = (bf16*)d_out;                 // bf16 in d_out

    dim3 blk(256);
    // ---- convert x once ----
    f2b<<<8192, blk, 0, stream>>>(x, xb, 2097152);
    // ---- fused A-projections: cq = xb @ [wkv_a; wq_a]^T (N=2624) ----
    f2b<<<2176, blk, 0, stream>>>(wkv_a, wslot, 557056);              // rows 0-1087
    f2b<<<3072, blk, 0, stream>>>(wq_a, wslot + 1088 * 2048, 786432); // rows 1088-2623
    // ragged N=2624: staging reads wslot rows up to 2687 (junk ok, cols>=2624
    // never stored); 2688*2048*2 = 11.01MB fits wslot region.
    gemm_bt<false><<<dim3(32, 21), blk, 0, stream>>>(xb, wslot, cq, 4096, 2624, 2048, 2048, 2048, 2624);
    // ---- KV path ----
    rope_k<<<512, blk, 0, stream>>>(cq, kpe, fcos, fsin);
    rmsnorm_ip<<<4096, blk, 0, stream>>>(cq, kv_norm_w, 1024, 2624);
    f2b<<<3072, blk, 0, stream>>>(wkv_b, wslot, 786432);   // 3072*1024/4
    gemm_bt<false><<<dim3(32, 24), blk, 0, stream>>>(cq, wslot, kv2, 4096, 3072, 1024, 2624, 1024, 3072);
    // ---- Q path (qa = cq cols 1088..2623; qbuf in d_out) ----
    rmsnorm_ip<<<4096, blk, 0, stream>>>(cq + 1088, q_norm_w, 1536, 2624);
    f2b<<<3072, blk, 0, stream>>>(wq_b, wslot, 786432);    // 2048*1536/4
    gemm_bt<false><<<dim3(32, 16), blk, 0, stream>>>(cq + 1088, wslot, qbuf, 4096, 2048, 1536, 2624, 1536, 2048);
    rope_q<<<8192, blk, 0, stream>>>(qbuf, fcos, fsin);
    // ---- attention (cq region becomes attno) ----
    attn_kernel<<<dim3(16, 16, 2), dim3(512), 0, stream>>>(qbuf, kv2, kpe, attno);
    // ---- output projection (fp32 store) ----
    f2b<<<4096, blk, 0, stream>>>(wo, wslot, 1048576);     // 2048*2048/4
    gemm_bt<true><<<dim3(32, 16), blk, 0, stream>>>(attno, wslot, out, 4096, 2048, 2048, 2048, 2048, 2048);
}

// Round 7
// 539.542 us; speedup vs baseline: 1.2362x; 1.0063x over previous
//
#include <hip/hip_runtime.h>
#include <hip/hip_bf16.h>

// MLA prefill: B=2,S=2048,D=2048,H=16,DQK=128(=64 nope+64 rope),DV=128,QLR=1536,KVLR=1024
// INPUTS FP32; OUTPUT FP32. R16 (post R15 attn-regression analysis):
//  - attn: R13 structure + CORRECTLY-PLACED T14: next tile's K/V loads are
//    issued AFTER barrier B (inside the compute region, before the causal
//    continue), so they fly during QK^T/softmax/PV and are drained at the
//    NEXT iteration's barrier A. (R15 issued them before barrier B, whose
//    implicit vmcnt(0) drained them on the spot -- that was the regression.)
//    T13 defer-rescale dropped (single-variable experiment vs R13).
//  - gemm side: unchanged from R15 (fused A-projection N=2624, 2-phase dbuf).
//  BANNED: divergent-base global_load_lds (R11/R12 container killer).
// No __expf (container-killer). No INFINITY (finite-math safe).
//
// Workspace map (74.98MB used; 80MB proven writable in R1):
//   kv2  @ 0         (4096x3072 bf16, 25.2MB)  live: kv2-gemm .. attn
//   kpe  @ 25165824  (4096x64  bf16,  0.5MB)   live: rope_k .. attn
//   cq   @ 25690112  (4096x2624 bf16, 21.5MB)  cols 0-1087=kvb, 1088-2623=qa
//                    reused as attno (4096x2048) after q_b gemm.
//   xb   @ 47185920  (4096x2048 bf16, 16.8MB)  live: cvt .. fused gemm
//   wslot@ 63963136  (11.0MB weight slot: wkv_a+wq_a fused / wkv_b / wq_b / wo)
//   qbuf (4096x2048 bf16) lives in d_out until out-gemm.

using bf16 = __hip_bfloat16;
typedef __attribute__((ext_vector_type(8))) short bf16x8;
typedef __attribute__((ext_vector_type(4))) float f32x4;

#define S_ 2048
#define NEG_BIG (-1e30f)
#define LOG2E 1.4426950408889634f

static __device__ __forceinline__ f32x4 mfma16(bf16x8 a, bf16x8 b, f32x4 c) {
    return __builtin_amdgcn_mfma_f32_16x16x32_bf16(a, b, c, 0, 0, 0);
}

// async global->LDS, 16B per lane. LDS dest must be lane-linear per wave;
// global src must be a single affine base (no divergent base select!).
static __device__ __forceinline__ void gload_lds16(const bf16* g, bf16* l) {
    __builtin_amdgcn_global_load_lds(
        (const __attribute__((address_space(1))) void*)g,
        (__attribute__((address_space(3))) void*)l, 16, 0, 0);
}

// ---------------------------------------------------------------------------
// fp32 -> bf16 bulk convert, 4 elems/thread.
// ---------------------------------------------------------------------------
__global__ __launch_bounds__(256) void f2b(const float* __restrict__ src,
                                           bf16* __restrict__ dst, int n4) {
    int i = blockIdx.x * 256 + threadIdx.x;
    if (i < n4) {
        float4 v = ((const float4*)src)[i];
        alignas(8) bf16 t[4];
        t[0] = (bf16)v.x; t[1] = (bf16)v.y; t[2] = (bf16)v.z; t[3] = (bf16)v.w;
        ((uint2*)dst)[i] = *(const uint2*)t;
    }
}

// ---------------------------------------------------------------------------
// GEMM: C[M,N] = A[M,K] @ B[N,K]^T. 128x128 tile, BK=32, 256 thr, bf16 in.
// Double-buffered staging via global_load_lds; swizzle on GLOBAL src address,
// LDS linear. One __syncthreads per K-step (implicit vmcnt+lgkm drain).
// NOTE: no N-guard in staging -- caller guarantees B rows up to grid.y*128
// readable (ragged N reads junk rows; cols>=N never stored).
// ---------------------------------------------------------------------------
template <bool C_F32>
__global__ __launch_bounds__(256) void gemm_bt(const bf16* __restrict__ A,
                                               const bf16* __restrict__ Bw,
                                               void* __restrict__ Cv,
                                               int M, int N, int K,
                                               int lda, int ldb, int ldc) {
    __shared__ bf16 As[2][128 * 32];
    __shared__ bf16 Bs[2][128 * 32];
    const int tid = threadIdx.x;
    const int m0 = blockIdx.x * 128;
    const int n0 = blockIdx.y * 128;
    const int w = tid >> 6, lane = tid & 63, quad = lane >> 4, l15 = lane & 15;
    const int wr = (w >> 1) * 64, wc = (w & 1) * 64;

    f32x4 acc[4][4];
#pragma unroll
    for (int i = 0; i < 4; i++)
#pragma unroll
        for (int j = 0; j < 4; j++) acc[i][j] = (f32x4){0.f, 0.f, 0.f, 0.f};

    auto stage = [&](int buf, int k0) {
#pragma unroll
        for (int cc = 0; cc < 2; cc++) {
            int c = tid + cc * 256;            // 512 chunks of 8 bf16 per matrix
            int row = c >> 2;
            int chunk = (c & 3) ^ ((row >> 1) & 3);  // pre-swizzled source
            gload_lds16(A + (size_t)(m0 + row) * lda + k0 + chunk * 8, &As[buf][c * 8]);
            gload_lds16(Bw + (size_t)(n0 + row) * ldb + k0 + chunk * 8, &Bs[buf][c * 8]);
        }
    };

    stage(0, 0);
    __syncthreads();                // drains vmcnt(0): buf0 ready
    int cur = 0;
    for (int k0 = 0; k0 < K; k0 += 32) {
        if (k0 + 32 < K) stage(cur ^ 1, k0 + 32);   // async prefetch next tile
        const bf16* Asc = As[cur];
        const bf16* Bsc = Bs[cur];
        bf16x8 af[4], bfr[4];
#pragma unroll
        for (int mi = 0; mi < 4; mi++) {
            int row = wr + mi * 16 + l15;
            int chunkE = quad ^ ((row >> 1) & 3);
            af[mi] = *(const bf16x8*)(&Asc[row * 32 + chunkE * 8]);
        }
#pragma unroll
        for (int ni = 0; ni < 4; ni++) {
            int row = wc + ni * 16 + l15;
            int chunkE = quad ^ ((row >> 1) & 3);
            bfr[ni] = *(const bf16x8*)(&Bsc[row * 32 + chunkE * 8]);
        }
#pragma unroll
        for (int mi = 0; mi < 4; mi++)
#pragma unroll
            for (int ni = 0; ni < 4; ni++)
                acc[mi][ni] = mfma16(af[mi], bfr[ni], acc[mi][ni]);
        __syncthreads();            // prefetch DMA + LDS reads drained; all waves
        cur ^= 1;
    }

#pragma unroll
    for (int mi = 0; mi < 4; mi++) {
#pragma unroll
        for (int ni = 0; ni < 4; ni++) {
            int col = n0 + wc + ni * 16 + l15;
            if (col < N) {
#pragma unroll
                for (int r = 0; r < 4; r++) {
                    int row = m0 + wr + mi * 16 + quad * 4 + r;
                    if (C_F32) ((float*)Cv)[(size_t)row * ldc + col] = acc[mi][ni][r];
                    else       ((bf16*)Cv)[(size_t)row * ldc + col] = (bf16)acc[mi][ni][r];
                }
            }
        }
    }
}

// ---------------------------------------------------------------------------
// In-place row RMSNorm on bf16 buffer, fp32 weight, fp32 stats.
// ---------------------------------------------------------------------------
__global__ void rmsnorm_ip(bf16* __restrict__ buf, const float* __restrict__ w,
                           int cols, int ld) {
    int row = blockIdx.x;
    bf16* p = buf + (size_t)row * ld;
    float ss = 0.f;
    for (int c = threadIdx.x; c < cols; c += 256) {
        float v = __bfloat162float(p[c]);
        ss += v * v;
    }
#pragma unroll
    for (int off = 32; off; off >>= 1) ss += __shfl_down(ss, off, 64);
    __shared__ float red[4];
    __shared__ float rnorm_s;
    if ((threadIdx.x & 63) == 0) red[threadIdx.x >> 6] = ss;
    __syncthreads();
    if (threadIdx.x == 0)
        rnorm_s = rsqrtf((red[0] + red[1] + red[2] + red[3]) / cols + 1e-6f);
    __syncthreads();
    float rn = rnorm_s;
    for (int c = threadIdx.x; c < cols; c += 256) {
        float v = __bfloat162float(p[c]);
        p[c] = (bf16)(v * rn * w[c]);
    }
}

// ---------------------------------------------------------------------------
// RoPE on k_pe: kpe[row,0..64) = rope(cq[row,1024..1088)). fp32 freqs.
// cq row stride 2624 (fused buffer).
// ---------------------------------------------------------------------------
__global__ void rope_k(const bf16* __restrict__ cq, bf16* __restrict__ kpe,
                       const float* __restrict__ fc, const float* __restrict__ fs) {
    int id = blockIdx.x * 256 + threadIdx.x;  // ROWS*32
    int row = id >> 5, i = id & 31;
    int s = row & (S_ - 1);
    const bf16* p = cq + (size_t)row * 2624 + 1024 + 2 * i;
    float x0 = __bfloat162float(p[0]), x1 = __bfloat162float(p[1]);
    float c = fc[s * 32 + i], sn = fs[s * 32 + i];
    bf16* q = kpe + (size_t)row * 64 + 2 * i;
    q[0] = (bf16)(x0 * c - x1 * sn);
    q[1] = (bf16)(x0 * sn + x1 * c);
}

// RoPE on q_pe, in-place on bf16 qbuf: [row, h*128+64 .. h*128+128)
__global__ void rope_q(bf16* __restrict__ qb, const float* __restrict__ fc,
                       const float* __restrict__ fs) {
    int id = blockIdx.x * 256 + threadIdx.x;  // ROWS*16*32
    int row = id >> 9, rest = id & 511, h = rest >> 5, i = rest & 31;
    int s = row & (S_ - 1);
    bf16* p = qb + (size_t)row * 2048 + h * 128 + 64 + 2 * i;
    float x0 = __bfloat162float(p[0]), x1 = __bfloat162float(p[1]);
    float c = fc[s * 32 + i], sn = fs[s * 32 + i];
    p[0] = (bf16)(x0 * c - x1 * sn);
    p[1] = (bf16)(x0 * sn + x1 * c);
}

// ---------------------------------------------------------------------------
// MFMA flash attention, causal, SWAPPED QK^T. Block = 512 thr = 8 waves,
// 2 groups x 4 waves; group 0 q-tile blockIdx.x, group 1 q-tile 31-x.
// R13-proven structure; T14 with CORRECT placement: next-tile loads issued
// after barrier B (in the compute region) so they fly under compute and are
// drained at the next iteration's barrier A.
// ---------------------------------------------------------------------------
__global__ __launch_bounds__(512) void attn_kernel(const bf16* __restrict__ Qg,
                                                   const bf16* __restrict__ KV2,
                                                   const bf16* __restrict__ KPE,
                                                   bf16* __restrict__ Og) {
    __shared__ bf16 Ks[64 * 128];       // [t][d], 16B-chunk swizzle cE = c8 ^ (t&7)
    __shared__ bf16 Vt[128 * 64];       // [dv][t], swizzle cE = (t>>3) ^ (dv&7)
    __shared__ bf16 Ps[8][16 * 64];     // per-wave P [q16][t64], cE = c8 ^ (q&7)
    const int tid = threadIdx.x;
    const int h = blockIdx.y;
    const int b = blockIdx.z;
    const int w = tid >> 6, lane = tid & 63, quad = lane >> 4, l15 = lane & 15;
    const int grp = w >> 2, wl = w & 3;
    const int jB = 31 - (int)blockIdx.x;
    const int q0 = (grp ? jB : (int)blockIdx.x) * 64;
    const int qrow = q0 + wl * 16 + l15;          // this lane's q row (in S)
    const float scl2 = 0.08838834764831845f * LOG2E;  // 1/sqrt(128) * log2(e)

    // Q as B-fragment: lane holds col q=l15(own row), k = kk*32 + quad*8 + j
    bf16x8 qf[4];
    {
        const bf16* qp = Qg + ((size_t)(b * S_) + qrow) * 2048 + h * 128 + quad * 8;
#pragma unroll
        for (int kk = 0; kk < 4; kk++) qf[kk] = *(const bf16x8*)(qp + kk * 32);
    }

    f32x4 acc_o[8];
#pragma unroll
    for (int j = 0; j < 8; j++) acc_o[j] = (f32x4){0.f, 0.f, 0.f, 0.f};
    float m_i = NEG_BIG, l_i = 0.f;               // per-lane (q = qrow)
    const int s_base = q0 + wl * 16 + quad * 4;   // acc_o row base (PV C-layout)
    const int tend = jB * 64;                     // block-uniform loop bound

    // V staging decomposition: thread -> 4t x 4dv transpose-in-regs
    const int dv0 = (tid >> 4) * 4;               // 0..124
    const int tv0 = (tid & 15) * 4;               // 0..60

    // T14 register carriers (static indexing only -- rule #20)
    int4 kreg0, kreg1;
    uint2 vreg0, vreg1, vreg2, vreg3;
    auto loadKV = [&](int t0) {
        {
            int c = tid;                           // chunk 0..511
            int trow = c >> 4, chunk = c & 15, col8 = chunk * 8;
            size_t grow = (size_t)(b * S_) + t0 + trow;
            kreg0 = (col8 < 64) ? *(const int4*)(KV2 + grow * 3072 + h * 192 + col8)
                                : *(const int4*)(KPE + grow * 64 + col8 - 64);
        }
        {
            int c = tid + 512;                     // chunk 512..1023
            int trow = c >> 4, chunk = c & 15, col8 = chunk * 8;
            size_t grow = (size_t)(b * S_) + t0 + trow;
            kreg1 = (col8 < 64) ? *(const int4*)(KV2 + grow * 3072 + h * 192 + col8)
                                : *(const int4*)(KPE + grow * 64 + col8 - 64);
        }
        size_t grow0 = (size_t)(b * S_) + t0 + tv0;
        const bf16* vb = KV2 + grow0 * 3072 + h * 192 + 64 + dv0;
        vreg0 = *(const uint2*)(vb);
        vreg1 = *(const uint2*)(vb + 3072);
        vreg2 = *(const uint2*)(vb + 6144);
        vreg3 = *(const uint2*)(vb + 9216);
    };
    auto writeKV = [&]() {
        {
            int c = tid;
            int trow = c >> 4, chunk = c & 15;
            int chunkE = chunk ^ (trow & 7);
            *(int4*)(&Ks[trow * 128 + chunkE * 8]) = kreg0;
        }
        {
            int c = tid + 512;
            int trow = c >> 4, chunk = c & 15;
            int chunkE = chunk ^ (trow & 7);
            *(int4*)(&Ks[trow * 128 + chunkE * 8]) = kreg1;
        }
        const bf16* v0 = (const bf16*)&vreg0;
        const bf16* v1 = (const bf16*)&vreg1;
        const bf16* v2 = (const bf16*)&vreg2;
        const bf16* v3 = (const bf16*)&vreg3;
#pragma unroll
        for (int j = 0; j < 4; j++) {
            alignas(8) bf16 tmp[4] = {v0[j], v1[j], v2[j], v3[j]};
            int dv = dv0 + j;
            int cE = (tv0 >> 3) ^ (dv & 7);
            *(uint2*)(&Vt[dv * 64 + cE * 8 + (tv0 & 7)]) = *(uint2*)tmp;
        }
    };

    loadKV(0);                                     // prologue issue
    for (int t0 = 0; t0 <= tend; t0 += 64) {
        __syncthreads();                 // barrier A: prev compute done; drains
                                         // in-flight loads (hidden under compute)
        writeKV();                       // vmcnt already satisfied; pure ds_write
        __syncthreads();                 // barrier B: tile visible (lgkm drain)
        if (t0 + 64 <= tend) loadKV(t0 + 64);  // issue DURING compute region
        if (t0 > q0) continue;           // causal range done; keep staging

        // ---- scores, swapped: sc[ni] = K_tile(ni) x Q  => D[t][q] ----
        f32x4 sc[4];
#pragma unroll
        for (int ni = 0; ni < 4; ni++) sc[ni] = (f32x4){0.f, 0.f, 0.f, 0.f};
#pragma unroll
        for (int kk = 0; kk < 4; kk++) {
#pragma unroll
            for (int ni = 0; ni < 4; ni++) {
                int trow = ni * 16 + l15;
                int chunkE = (kk * 4 + quad) ^ (trow & 7);
                bf16x8 kf = *(const bf16x8*)(&Ks[trow * 128 + chunkE * 8]);
                sc[ni] = mfma16(kf, qf[kk], sc[ni]);   // A=K rows t, B=Q cols q
            }
        }
        // ---- per-lane softmax over the full row (t in lane) ----
        float xv[4][4];
        float pmax = NEG_BIG;
#pragma unroll
        for (int ni = 0; ni < 4; ni++) {
#pragma unroll
            for (int r = 0; r < 4; r++) {
                int t = t0 + ni * 16 + quad * 4 + r;
                float x = sc[ni][r] * scl2;
                if (t > qrow) x = NEG_BIG;
                xv[ni][r] = x;
                pmax = fmaxf(pmax, x);
            }
        }
        pmax = fmaxf(pmax, __shfl_xor(pmax, 16, 64));
        pmax = fmaxf(pmax, __shfl_xor(pmax, 32, 64));
        float mn = fmaxf(m_i, pmax);
        float alpha = exp2f(m_i - mn);
        m_i = mn;
        float rsum = 0.f;
#pragma unroll
        for (int ni = 0; ni < 4; ni++)
#pragma unroll
            for (int r = 0; r < 4; r++) {
                float e = exp2f(xv[ni][r] - mn);
                xv[ni][r] = e;
                rsum += e;
            }
        rsum += __shfl_xor(rsum, 16, 64);
        rsum += __shfl_xor(rsum, 32, 64);
        l_i = l_i * alpha + rsum;
        // alpha for acc_o rows (q-in-16 = quad*4+r) lives at lane l15=quad*4+r
        float ar[4];
#pragma unroll
        for (int r = 0; r < 4; r++) ar[r] = __shfl(alpha, quad * 4 + r, 64);
#pragma unroll
        for (int nj = 0; nj < 8; nj++)
#pragma unroll
            for (int r = 0; r < 4; r++) acc_o[nj][r] *= ar[r];

        // ---- P -> LDS: 4 packed b64 writes (t runs of 4 in-lane) ----
#pragma unroll
        for (int ni = 0; ni < 4; ni++) {
            int tb = ni * 16 + quad * 4;          // t base (elems)
            int cE = (tb >> 3) ^ (l15 & 7);
            alignas(8) bf16 tmp[4] = {(bf16)xv[ni][0], (bf16)xv[ni][1],
                                      (bf16)xv[ni][2], (bf16)xv[ni][3]};
            *(uint2*)(&Ps[w][l15 * 64 + cE * 8 + (tb & 7)]) = *(uint2*)tmp;
        }
        // ---- O += P @ V (wave-private Ps; in-wave DS ordering suffices) ----
#pragma unroll
        for (int kk2 = 0; kk2 < 2; kk2++) {
            int cEp = (kk2 * 4 + quad) ^ (l15 & 7);
            bf16x8 pf = *(const bf16x8*)(&Ps[w][l15 * 64 + cEp * 8]);
#pragma unroll
            for (int nj = 0; nj < 8; nj++) {
                int dv = nj * 16 + l15;
                int chunkE = (kk2 * 4 + quad) ^ (dv & 7);
                bf16x8 vf = *(const bf16x8*)(&Vt[dv * 64 + chunkE * 8]);
                acc_o[nj] = mfma16(pf, vf, acc_o[nj]);
            }
        }
    }
    // epilogue: l for acc rows fetched from lane l15 = quad*4+r
    float lr[4];
#pragma unroll
    for (int r = 0; r < 4; r++) lr[r] = __shfl(l_i, quad * 4 + r, 64);
#pragma unroll
    for (int nj = 0; nj < 8; nj++) {
        int col = h * 128 + nj * 16 + l15;
#pragma unroll
        for (int r = 0; r < 4; r++) {
            float v = acc_o[nj][r] / lr[r];
            Og[((size_t)(b * S_) + s_base + r) * 2048 + col] = (bf16)v;
        }
    }
}

// ---------------------------------------------------------------------------
extern "C" void kernel_launch(void* const* d_in, const int* in_sizes, int n_in,
                              void* d_out, int out_size, void* d_ws, size_t ws_size,
                              hipStream_t stream) {
    const float* x        = (const float*)d_in[0];   // (4096, 2048) fp32
    const float* wq_a     = (const float*)d_in[1];   // (1536, 2048) fp32
    const float* q_norm_w = (const float*)d_in[2];   // (1536,) fp32
    const float* wq_b     = (const float*)d_in[3];   // (2048, 1536) fp32
    const float* wkv_a    = (const float*)d_in[4];   // (1088, 2048) fp32
    const float* kv_norm_w= (const float*)d_in[5];   // (1024,) fp32
    const float* wkv_b    = (const float*)d_in[6];   // (3072, 1024) fp32
    const float* wo       = (const float*)d_in[7];   // (2048, 2048) fp32
    const float* fcos     = (const float*)d_in[9];   // (2048, 32) fp32
    const float* fsin     = (const float*)d_in[10];  // (2048, 32) fp32
    float* out = (float*)d_out;                      // (4096, 2048) fp32

    char* ws = (char*)d_ws;
    bf16* kv2   = (bf16*)(ws);                  // 25.2MB
    bf16* kpe   = (bf16*)(ws + 25165824);       // 0.5MB
    bf16* cq    = (bf16*)(ws + 25690112);       // 21.5MB combined kvb|qa; attno later
    bf16* xb    = (bf16*)(ws + 47185920);       // 16.8MB
    bf16* wslot = (bf16*)(ws + 63963136);       // 11.0MB weight slot
    bf16* attno = cq;                           // reuse after q_b gemm
    bf16* qbuf  = (bf16*)d_out;                 // bf16 in d_out

    dim3 blk(256);
    // ---- convert x once ----
    f2b<<<8192, blk, 0, stream>>>(x, xb, 2097152);
    // ---- fused A-projections: cq = xb @ [wkv_a; wq_a]^T (N=2624) ----
    f2b<<<2176, blk, 0, stream>>>(wkv_a, wslot, 557056);              // rows 0-1087
    f2b<<<3072, blk, 0, stream>>>(wq_a, wslot + 1088 * 2048, 786432); // rows 1088-2623
    // ragged N=2624: staging reads wslot rows up to 2687 (junk ok, cols>=2624
    // never stored); 2688*2048*2 = 11.01MB fits wslot region.
    gemm_bt<false><<<dim3(32, 21), blk, 0, stream>>>(xb, wslot, cq, 4096, 2624, 2048, 2048, 2048, 2624);
    // ---- KV path ----
    rope_k<<<512, blk, 0, stream>>>(cq, kpe, fcos, fsin);
    rmsnorm_ip<<<4096, blk, 0, stream>>>(cq, kv_norm_w, 1024, 2624);
    f2b<<<3072, blk, 0, stream>>>(wkv_b, wslot, 786432);   // 3072*1024/4
    gemm_bt<false><<<dim3(32, 24), blk, 0, stream>>>(cq, wslot, kv2, 4096, 3072, 1024, 2624, 1024, 3072);
    // ---- Q path (qa = cq cols 1088..2623; qbuf in d_out) ----
    rmsnorm_ip<<<4096, blk, 0, stream>>>(cq + 1088, q_norm_w, 1536, 2624);
    f2b<<<3072, blk, 0, stream>>>(wq_b, wslot, 786432);    // 2048*1536/4
    gemm_bt<false><<<dim3(32, 16), blk, 0, stream>>>(cq + 1088, wslot, qbuf, 4096, 2048, 1536, 2624, 1536, 2048);
    rope_q<<<8192, blk, 0, stream>>>(qbuf, fcos, fsin);
    // ---- attention (cq region becomes attno) ----
    attn_kernel<<<dim3(16, 16, 2), dim3(512), 0, stream>>>(qbuf, kv2, kpe, attno);
    // ---- output projection (fp32 store) ----
    f2b<<<4096, blk, 0, stream>>>(wo, wslot, 1048576);     // 2048*2048/4
    gemm_bt<true><<<dim3(32, 16), blk, 0, stream>>>(attno, wslot, out, 4096, 2048, 2048, 2048, 2048, 2048);
}

// Round 8
// 477.402 us; speedup vs baseline: 1.3972x; 1.1302x over previous
//
#include <hip/hip_runtime.h>
#include <hip/hip_bf16.h>

// MLA prefill: B=2,S=2048,D=2048,H=16,DQK=128(=64 nope+64 rope),DV=128,QLR=1536,KVLR=1024
// INPUTS FP32; OUTPUT FP32. R17 (post R15/R16 T14 failures):
//  - attn: R13-EXACT staging (stage->barrier->compute; no register carriers --
//    T14 abandoned: both placements cost occupancy, 35%->18%, and regressed)
//    + T13 defer-rescale only (zero-VGPR lever): skip alpha-rescale when
//    __all(pmax - m_i <= 8); P bounded by 2^8, bf16-safe (HK THR=8).
//  - gemm side: unchanged from R15/R16 (fused A-projection N=2624, 2-ph dbuf).
//  BANNED: divergent-base global_load_lds (R11/R12 container killer).
//  ABANDONED: T14 reg-carrier staging (R15: -67us, R16: -59us vs R13).
// No __expf (container-killer). No INFINITY (finite-math safe).
//
// Workspace map (74.98MB used; 80MB proven writable in R1):
//   kv2  @ 0         (4096x3072 bf16, 25.2MB)  live: kv2-gemm .. attn
//   kpe  @ 25165824  (4096x64  bf16,  0.5MB)   live: rope_k .. attn
//   cq   @ 25690112  (4096x2624 bf16, 21.5MB)  cols 0-1087=kvb, 1088-2623=qa
//                    reused as attno (4096x2048) after q_b gemm.
//   xb   @ 47185920  (4096x2048 bf16, 16.8MB)  live: cvt .. fused gemm
//   wslot@ 63963136  (11.0MB weight slot: wkv_a+wq_a fused / wkv_b / wq_b / wo)
//   qbuf (4096x2048 bf16) lives in d_out until out-gemm.

using bf16 = __hip_bfloat16;
typedef __attribute__((ext_vector_type(8))) short bf16x8;
typedef __attribute__((ext_vector_type(4))) float f32x4;

#define S_ 2048
#define NEG_BIG (-1e30f)
#define LOG2E 1.4426950408889634f

static __device__ __forceinline__ f32x4 mfma16(bf16x8 a, bf16x8 b, f32x4 c) {
    return __builtin_amdgcn_mfma_f32_16x16x32_bf16(a, b, c, 0, 0, 0);
}

// async global->LDS, 16B per lane. LDS dest must be lane-linear per wave;
// global src must be a single affine base (no divergent base select!).
static __device__ __forceinline__ void gload_lds16(const bf16* g, bf16* l) {
    __builtin_amdgcn_global_load_lds(
        (const __attribute__((address_space(1))) void*)g,
        (__attribute__((address_space(3))) void*)l, 16, 0, 0);
}

// ---------------------------------------------------------------------------
// fp32 -> bf16 bulk convert, 4 elems/thread.
// ---------------------------------------------------------------------------
__global__ __launch_bounds__(256) void f2b(const float* __restrict__ src,
                                           bf16* __restrict__ dst, int n4) {
    int i = blockIdx.x * 256 + threadIdx.x;
    if (i < n4) {
        float4 v = ((const float4*)src)[i];
        alignas(8) bf16 t[4];
        t[0] = (bf16)v.x; t[1] = (bf16)v.y; t[2] = (bf16)v.z; t[3] = (bf16)v.w;
        ((uint2*)dst)[i] = *(const uint2*)t;
    }
}

// ---------------------------------------------------------------------------
// GEMM: C[M,N] = A[M,K] @ B[N,K]^T. 128x128 tile, BK=32, 256 thr, bf16 in.
// Double-buffered staging via global_load_lds; swizzle on GLOBAL src address,
// LDS linear. One __syncthreads per K-step (implicit vmcnt+lgkm drain).
// NOTE: no N-guard in staging -- caller guarantees B rows up to grid.y*128
// readable (ragged N reads junk rows; cols>=N never stored).
// ---------------------------------------------------------------------------
template <bool C_F32>
__global__ __launch_bounds__(256) void gemm_bt(const bf16* __restrict__ A,
                                               const bf16* __restrict__ Bw,
                                               void* __restrict__ Cv,
                                               int M, int N, int K,
                                               int lda, int ldb, int ldc) {
    __shared__ bf16 As[2][128 * 32];
    __shared__ bf16 Bs[2][128 * 32];
    const int tid = threadIdx.x;
    const int m0 = blockIdx.x * 128;
    const int n0 = blockIdx.y * 128;
    const int w = tid >> 6, lane = tid & 63, quad = lane >> 4, l15 = lane & 15;
    const int wr = (w >> 1) * 64, wc = (w & 1) * 64;

    f32x4 acc[4][4];
#pragma unroll
    for (int i = 0; i < 4; i++)
#pragma unroll
        for (int j = 0; j < 4; j++) acc[i][j] = (f32x4){0.f, 0.f, 0.f, 0.f};

    auto stage = [&](int buf, int k0) {
#pragma unroll
        for (int cc = 0; cc < 2; cc++) {
            int c = tid + cc * 256;            // 512 chunks of 8 bf16 per matrix
            int row = c >> 2;
            int chunk = (c & 3) ^ ((row >> 1) & 3);  // pre-swizzled source
            gload_lds16(A + (size_t)(m0 + row) * lda + k0 + chunk * 8, &As[buf][c * 8]);
            gload_lds16(Bw + (size_t)(n0 + row) * ldb + k0 + chunk * 8, &Bs[buf][c * 8]);
        }
    };

    stage(0, 0);
    __syncthreads();                // drains vmcnt(0): buf0 ready
    int cur = 0;
    for (int k0 = 0; k0 < K; k0 += 32) {
        if (k0 + 32 < K) stage(cur ^ 1, k0 + 32);   // async prefetch next tile
        const bf16* Asc = As[cur];
        const bf16* Bsc = Bs[cur];
        bf16x8 af[4], bfr[4];
#pragma unroll
        for (int mi = 0; mi < 4; mi++) {
            int row = wr + mi * 16 + l15;
            int chunkE = quad ^ ((row >> 1) & 3);
            af[mi] = *(const bf16x8*)(&Asc[row * 32 + chunkE * 8]);
        }
#pragma unroll
        for (int ni = 0; ni < 4; ni++) {
            int row = wc + ni * 16 + l15;
            int chunkE = quad ^ ((row >> 1) & 3);
            bfr[ni] = *(const bf16x8*)(&Bsc[row * 32 + chunkE * 8]);
        }
#pragma unroll
        for (int mi = 0; mi < 4; mi++)
#pragma unroll
            for (int ni = 0; ni < 4; ni++)
                acc[mi][ni] = mfma16(af[mi], bfr[ni], acc[mi][ni]);
        __syncthreads();            // prefetch DMA + LDS reads drained; all waves
        cur ^= 1;
    }

#pragma unroll
    for (int mi = 0; mi < 4; mi++) {
#pragma unroll
        for (int ni = 0; ni < 4; ni++) {
            int col = n0 + wc + ni * 16 + l15;
            if (col < N) {
#pragma unroll
                for (int r = 0; r < 4; r++) {
                    int row = m0 + wr + mi * 16 + quad * 4 + r;
                    if (C_F32) ((float*)Cv)[(size_t)row * ldc + col] = acc[mi][ni][r];
                    else       ((bf16*)Cv)[(size_t)row * ldc + col] = (bf16)acc[mi][ni][r];
                }
            }
        }
    }
}

// ---------------------------------------------------------------------------
// In-place row RMSNorm on bf16 buffer, fp32 weight, fp32 stats.
// ---------------------------------------------------------------------------
__global__ void rmsnorm_ip(bf16* __restrict__ buf, const float* __restrict__ w,
                           int cols, int ld) {
    int row = blockIdx.x;
    bf16* p = buf + (size_t)row * ld;
    float ss = 0.f;
    for (int c = threadIdx.x; c < cols; c += 256) {
        float v = __bfloat162float(p[c]);
        ss += v * v;
    }
#pragma unroll
    for (int off = 32; off; off >>= 1) ss += __shfl_down(ss, off, 64);
    __shared__ float red[4];
    __shared__ float rnorm_s;
    if ((threadIdx.x & 63) == 0) red[threadIdx.x >> 6] = ss;
    __syncthreads();
    if (threadIdx.x == 0)
        rnorm_s = rsqrtf((red[0] + red[1] + red[2] + red[3]) / cols + 1e-6f);
    __syncthreads();
    float rn = rnorm_s;
    for (int c = threadIdx.x; c < cols; c += 256) {
        float v = __bfloat162float(p[c]);
        p[c] = (bf16)(v * rn * w[c]);
    }
}

// ---------------------------------------------------------------------------
// RoPE on k_pe: kpe[row,0..64) = rope(cq[row,1024..1088)). fp32 freqs.
// cq row stride 2624 (fused buffer).
// ---------------------------------------------------------------------------
__global__ void rope_k(const bf16* __restrict__ cq, bf16* __restrict__ kpe,
                       const float* __restrict__ fc, const float* __restrict__ fs) {
    int id = blockIdx.x * 256 + threadIdx.x;  // ROWS*32
    int row = id >> 5, i = id & 31;
    int s = row & (S_ - 1);
    const bf16* p = cq + (size_t)row * 2624 + 1024 + 2 * i;
    float x0 = __bfloat162float(p[0]), x1 = __bfloat162float(p[1]);
    float c = fc[s * 32 + i], sn = fs[s * 32 + i];
    bf16* q = kpe + (size_t)row * 64 + 2 * i;
    q[0] = (bf16)(x0 * c - x1 * sn);
    q[1] = (bf16)(x0 * sn + x1 * c);
}

// RoPE on q_pe, in-place on bf16 qbuf: [row, h*128+64 .. h*128+128)
__global__ void rope_q(bf16* __restrict__ qb, const float* __restrict__ fc,
                       const float* __restrict__ fs) {
    int id = blockIdx.x * 256 + threadIdx.x;  // ROWS*16*32
    int row = id >> 9, rest = id & 511, h = rest >> 5, i = rest & 31;
    int s = row & (S_ - 1);
    bf16* p = qb + (size_t)row * 2048 + h * 128 + 64 + 2 * i;
    float x0 = __bfloat162float(p[0]), x1 = __bfloat162float(p[1]);
    float c = fc[s * 32 + i], sn = fs[s * 32 + i];
    p[0] = (bf16)(x0 * c - x1 * sn);
    p[1] = (bf16)(x0 * sn + x1 * c);
}

// ---------------------------------------------------------------------------
// MFMA flash attention, causal, SWAPPED QK^T. Block = 512 thr = 8 waves,
// 2 groups x 4 waves; group 0 q-tile blockIdx.x, group 1 q-tile 31-x.
// R13-EXACT staging (stage->barrier->compute) + T13 defer-rescale.
// Each lane's q-row: qrow = q0 + wl*16 + l15. sc = mfma(K,Q) => D[t][q]:
// row max/sum in-lane + shfl_xor(16|32); m/l per-lane scalars.
// ---------------------------------------------------------------------------
__global__ __launch_bounds__(512) void attn_kernel(const bf16* __restrict__ Qg,
                                                   const bf16* __restrict__ KV2,
                                                   const bf16* __restrict__ KPE,
                                                   bf16* __restrict__ Og) {
    __shared__ bf16 Ks[64 * 128];       // [t][d], 16B-chunk swizzle cE = c8 ^ (t&7)
    __shared__ bf16 Vt[128 * 64];       // [dv][t], swizzle cE = (t>>3) ^ (dv&7)
    __shared__ bf16 Ps[8][16 * 64];     // per-wave P [q16][t64], cE = c8 ^ (q&7)
    const int tid = threadIdx.x;
    const int h = blockIdx.y;
    const int b = blockIdx.z;
    const int w = tid >> 6, lane = tid & 63, quad = lane >> 4, l15 = lane & 15;
    const int grp = w >> 2, wl = w & 3;
    const int jB = 31 - (int)blockIdx.x;
    const int q0 = (grp ? jB : (int)blockIdx.x) * 64;
    const int qrow = q0 + wl * 16 + l15;          // this lane's q row (in S)
    const float scl2 = 0.08838834764831845f * LOG2E;  // 1/sqrt(128) * log2(e)

    // Q as B-fragment: lane holds col q=l15(own row), k = kk*32 + quad*8 + j
    bf16x8 qf[4];
    {
        const bf16* qp = Qg + ((size_t)(b * S_) + qrow) * 2048 + h * 128 + quad * 8;
#pragma unroll
        for (int kk = 0; kk < 4; kk++) qf[kk] = *(const bf16x8*)(qp + kk * 32);
    }

    f32x4 acc_o[8];
#pragma unroll
    for (int j = 0; j < 8; j++) acc_o[j] = (f32x4){0.f, 0.f, 0.f, 0.f};
    float m_i = NEG_BIG, l_i = 0.f;               // per-lane (q = qrow)
    const int s_base = q0 + wl * 16 + quad * 4;   // acc_o row base (PV C-layout)
    const int tend = jB * 64;                     // block-uniform loop bound

    // V staging decomposition: thread -> 4t x 4dv transpose-in-regs
    const int dv0 = (tid >> 4) * 4;               // 0..124
    const int tv0 = (tid & 15) * 4;               // 0..60

    for (int t0 = 0; t0 <= tend; t0 += 64) {
        __syncthreads();
        // ---- stage K: register int4 + swizzled ds_write (R13-proven) ----
#pragma unroll
        for (int cc = 0; cc < 2; cc++) {
            int c = tid + cc * 512;               // 1024 chunks of 8
            int trow = c >> 4, chunk = c & 15;
            int col8 = chunk * 8;
            size_t grow = (size_t)(b * S_) + t0 + trow;
            int4 v;
            if (col8 < 64) v = *(const int4*)(KV2 + grow * 3072 + h * 192 + col8);
            else           v = *(const int4*)(KPE + grow * 64 + col8 - 64);
            int chunkE = chunk ^ (trow & 7);
            *(int4*)(&Ks[trow * 128 + chunkE * 8]) = v;
        }
        // ---- stage V: 4x4 register transpose, 4 ds_write_b64/thread ----
        {
            size_t grow0 = (size_t)(b * S_) + t0 + tv0;
            alignas(16) bf16 va[4][4];
#pragma unroll
            for (int i = 0; i < 4; i++)
                *(uint2*)va[i] = *(const uint2*)(KV2 + (grow0 + i) * 3072 + h * 192 + 64 + dv0);
#pragma unroll
            for (int j = 0; j < 4; j++) {
                alignas(8) bf16 tmp[4] = {va[0][j], va[1][j], va[2][j], va[3][j]};
                int dv = dv0 + j;
                int cE = (tv0 >> 3) ^ (dv & 7);
                *(uint2*)(&Vt[dv * 64 + cE * 8 + (tv0 & 7)]) = *(uint2*)tmp;
            }
        }
        __syncthreads();
        if (t0 > q0) continue;   // this group's causal range done; keep staging

        // ---- scores, swapped: sc[ni] = K_tile(ni) x Q  => D[t][q] ----
        f32x4 sc[4];
#pragma unroll
        for (int ni = 0; ni < 4; ni++) sc[ni] = (f32x4){0.f, 0.f, 0.f, 0.f};
#pragma unroll
        for (int kk = 0; kk < 4; kk++) {
#pragma unroll
            for (int ni = 0; ni < 4; ni++) {
                int trow = ni * 16 + l15;
                int chunkE = (kk * 4 + quad) ^ (trow & 7);
                bf16x8 kf = *(const bf16x8*)(&Ks[trow * 128 + chunkE * 8]);
                sc[ni] = mfma16(kf, qf[kk], sc[ni]);   // A=K rows t, B=Q cols q
            }
        }
        // ---- per-lane softmax over the full row (t in lane) ----
        float xv[4][4];
        float pmax = NEG_BIG;
#pragma unroll
        for (int ni = 0; ni < 4; ni++) {
#pragma unroll
            for (int r = 0; r < 4; r++) {
                int t = t0 + ni * 16 + quad * 4 + r;
                float x = sc[ni][r] * scl2;
                if (t > qrow) x = NEG_BIG;
                xv[ni][r] = x;
                pmax = fmaxf(pmax, x);
            }
        }
        pmax = fmaxf(pmax, __shfl_xor(pmax, 16, 64));
        pmax = fmaxf(pmax, __shfl_xor(pmax, 32, 64));
        // T13 defer-rescale: only rescale when max grew by > 8 (P <= 2^8).
        // First tile: m_i = -1e30 -> always takes the rescale path.
        if (!__all(pmax - m_i <= 8.0f)) {
            float mn = fmaxf(m_i, pmax);
            float alpha = exp2f(m_i - mn);
            m_i = mn;
            l_i *= alpha;
            float ar[4];
#pragma unroll
            for (int r = 0; r < 4; r++) ar[r] = __shfl(alpha, quad * 4 + r, 64);
#pragma unroll
            for (int nj = 0; nj < 8; nj++)
#pragma unroll
                for (int r = 0; r < 4; r++) acc_o[nj][r] *= ar[r];
        }
        float rsum = 0.f;
#pragma unroll
        for (int ni = 0; ni < 4; ni++)
#pragma unroll
            for (int r = 0; r < 4; r++) {
                float e = exp2f(xv[ni][r] - m_i);
                xv[ni][r] = e;
                rsum += e;
            }
        rsum += __shfl_xor(rsum, 16, 64);
        rsum += __shfl_xor(rsum, 32, 64);
        l_i += rsum;

        // ---- P -> LDS: 4 packed b64 writes (t runs of 4 in-lane) ----
#pragma unroll
        for (int ni = 0; ni < 4; ni++) {
            int tb = ni * 16 + quad * 4;          // t base (elems)
            int cE = (tb >> 3) ^ (l15 & 7);
            alignas(8) bf16 tmp[4] = {(bf16)xv[ni][0], (bf16)xv[ni][1],
                                      (bf16)xv[ni][2], (bf16)xv[ni][3]};
            *(uint2*)(&Ps[w][l15 * 64 + cE * 8 + (tb & 7)]) = *(uint2*)tmp;
        }
        // ---- O += P @ V (wave-private Ps; in-wave DS ordering suffices) ----
#pragma unroll
        for (int kk2 = 0; kk2 < 2; kk2++) {
            int cEp = (kk2 * 4 + quad) ^ (l15 & 7);
            bf16x8 pf = *(const bf16x8*)(&Ps[w][l15 * 64 + cEp * 8]);
#pragma unroll
            for (int nj = 0; nj < 8; nj++) {
                int dv = nj * 16 + l15;
                int chunkE = (kk2 * 4 + quad) ^ (dv & 7);
                bf16x8 vf = *(const bf16x8*)(&Vt[dv * 64 + chunkE * 8]);
                acc_o[nj] = mfma16(pf, vf, acc_o[nj]);
            }
        }
    }
    // epilogue: l for acc rows fetched from lane l15 = quad*4+r
    float lr[4];
#pragma unroll
    for (int r = 0; r < 4; r++) lr[r] = __shfl(l_i, quad * 4 + r, 64);
#pragma unroll
    for (int nj = 0; nj < 8; nj++) {
        int col = h * 128 + nj * 16 + l15;
#pragma unroll
        for (int r = 0; r < 4; r++) {
            float v = acc_o[nj][r] / lr[r];
            Og[((size_t)(b * S_) + s_base + r) * 2048 + col] = (bf16)v;
        }
    }
}

// ---------------------------------------------------------------------------
extern "C" void kernel_launch(void* const* d_in, const int* in_sizes, int n_in,
                              void* d_out, int out_size, void* d_ws, size_t ws_size,
                              hipStream_t stream) {
    const float* x        = (const float*)d_in[0];   // (4096, 2048) fp32
    const float* wq_a     = (const float*)d_in[1];   // (1536, 2048) fp32
    const float* q_norm_w = (const float*)d_in[2];   // (1536,) fp32
    const float* wq_b     = (const float*)d_in[3];   // (2048, 1536) fp32
    const float* wkv_a    = (const float*)d_in[4];   // (1088, 2048) fp32
    const float* kv_norm_w= (const float*)d_in[5];   // (1024,) fp32
    const float* wkv_b    = (const float*)d_in[6];   // (3072, 1024) fp32
    const float* wo       = (const float*)d_in[7];   // (2048, 2048) fp32
    const float* fcos     = (const float*)d_in[9];   // (2048, 32) fp32
    const float* fsin     = (const float*)d_in[10];  // (2048, 32) fp32
    float* out = (float*)d_out;                      // (4096, 2048) fp32

    char* ws = (char*)d_ws;
    bf16* kv2   = (bf16*)(ws);                  // 25.2MB
    bf16* kpe   = (bf16*)(ws + 25165824);       // 0.5MB
    bf16* cq    = (bf16*)(ws + 25690112);       // 21.5MB combined kvb|qa; attno later
    bf16* xb    = (bf16*)(ws + 47185920);       // 16.8MB
    bf16* wslot = (bf16*)(ws + 63963136);       // 11.0MB weight slot
    bf16* attno = cq;                           // reuse after q_b gemm
    bf16* qbuf  = (bf16*)d_out;                 // bf16 in d_out

    dim3 blk(256);
    // ---- convert x once ----
    f2b<<<8192, blk, 0, stream>>>(x, xb, 2097152);
    // ---- fused A-projections: cq = xb @ [wkv_a; wq_a]^T (N=2624) ----
    f2b<<<2176, blk, 0, stream>>>(wkv_a, wslot, 557056);              // rows 0-1087
    f2b<<<3072, blk, 0, stream>>>(wq_a, wslot + 1088 * 2048, 786432); // rows 1088-2623
    // ragged N=2624: staging reads wslot rows up to 2687 (junk ok, cols>=2624
    // never stored); 2688*2048*2 = 11.01MB fits wslot region.
    gemm_bt<false><<<dim3(32, 21), blk, 0, stream>>>(xb, wslot, cq, 4096, 2624, 2048, 2048, 2048, 2624);
    // ---- KV path ----
    rope_k<<<512, blk, 0, stream>>>(cq, kpe, fcos, fsin);
    rmsnorm_ip<<<4096, blk, 0, stream>>>(cq, kv_norm_w, 1024, 2624);
    f2b<<<3072, blk, 0, stream>>>(wkv_b, wslot, 786432);   // 3072*1024/4
    gemm_bt<false><<<dim3(32, 24), blk, 0, stream>>>(cq, wslot, kv2, 4096, 3072, 1024, 2624, 1024, 3072);
    // ---- Q path (qa = cq cols 1088..2623; qbuf in d_out) ----
    rmsnorm_ip<<<4096, blk, 0, stream>>>(cq + 1088, q_norm_w, 1536, 2624);
    f2b<<<3072, blk, 0, stream>>>(wq_b, wslot, 786432);    // 2048*1536/4
    gemm_bt<false><<<dim3(32, 16), blk, 0, stream>>>(cq + 1088, wslot, qbuf, 4096, 2048, 1536, 2624, 1536, 2048);
    rope_q<<<8192, blk, 0, stream>>>(qbuf, fcos, fsin);
    // ---- attention (cq region becomes attno) ----
    attn_kernel<<<dim3(16, 16, 2), dim3(512), 0, stream>>>(qbuf, kv2, kpe, attno);
    // ---- output projection (fp32 store) ----
    f2b<<<4096, blk, 0, stream>>>(wo, wslot, 1048576);     // 2048*2048/4
    gemm_bt<true><<<dim3(32, 16), blk, 0, stream>>>(attno, wslot, out, 4096, 2048, 2048, 2048, 2048, 2048);
}